// Round 3
// baseline (682.724 us; speedup 1.0000x reference)
//
#include <hip/hip_runtime.h>
#include <hip/hip_bf16.h>

// InterestEvolve: attention-modulated GRU scan. B=2048, T=200, D=128, U=128.
//
// R11 = hybrid of R8 (structure) + R9/R10 (staging elimination).
//  - 8 waves x 16 gatecols, 512 threads, launch_bounds(512,2): 2 waves/SIMD
//    restores the latency hiding R9 lost (R9's 1 wave/SIMD regressed 254->333us
//    despite halving LDS traffic: scan steps are latency-bound, not LDS-BW-bound).
//  - x and Att loaded GLOBAL-DIRECT with register prefetch (x: 1 step ahead,
//    Att: 3-deep ring), bf16-converted in-register. No x_sm/a_sm, no chunk
//    staging, no staging barriers, no staged-write bank conflicts.
//  - Barriers are raw s_waitcnt(lgkmcnt)+s_barrier with sched_barrier(0)
//    hardening on both sides (rule #18): prefetch loads stay in flight.
//  - Step 0 special-cased (h=0 => x-part only): no LDS zero-init needed,
//    both exchange buffers fully written before any read.
//  - R8 schedule kept: x-part accumulators for step t+1 computed at the tail
//    of region 2 of step t (off critical path), biases preloaded into MFMA C,
//    K-major padded LDS (KCS=136, conflict-free b128 reads), 2+2 split chains.
// 128 blocks x 512 threads.

#define T_LEN 200
#define D_DIM 128
#define U_DIM 128
#define BM    16
#define KCS   136          // ushorts per slot-row: 16 batch * 8 cols + 8 pad
#define XSTEP (16 * KCS)   // ushorts per h/rh buffer (2176)

typedef __attribute__((ext_vector_type(8))) short bf16x8;
typedef __attribute__((ext_vector_type(4))) float f32x4;
typedef __attribute__((ext_vector_type(4))) unsigned int uint4v;

#define MFMA __builtin_amdgcn_mfma_f32_16x16x32_bf16

static __device__ __forceinline__ unsigned short f2bf(float f) {
    unsigned int u = __builtin_bit_cast(unsigned int, f);
    u += 0x7fffu + ((u >> 16) & 1u);       // round-to-nearest-even
    return (unsigned short)(u >> 16);
}
static __device__ __forceinline__ unsigned int pkbf2(float a, float b) {
    float2 t; t.x = a; t.y = b;
    __hip_bfloat162 v = __float22bfloat162_rn(t);   // v_cvt_pk_bf16_f32
    unsigned int u; __builtin_memcpy(&u, &v, 4);
    return u;
}
static __device__ __forceinline__ bf16x8 pack8bf(f32x4 lo, f32x4 hi) {
    uint4v v;
    v[0] = pkbf2(lo[0], lo[1]); v[1] = pkbf2(lo[2], lo[3]);
    v[2] = pkbf2(hi[0], hi[1]); v[3] = pkbf2(hi[2], hi[3]);
    return __builtin_bit_cast(bf16x8, v);
}
static __device__ __forceinline__ float fast_exp2(float x) {
#if __has_builtin(__builtin_amdgcn_exp2f)
    return __builtin_amdgcn_exp2f(x);
#else
    return exp2f(x);
#endif
}
static __device__ __forceinline__ float fast_rcp(float x) {
#if __has_builtin(__builtin_amdgcn_rcpf)
    return __builtin_amdgcn_rcpf(x);
#else
    return 1.0f / x;
#endif
}
// Barrier that waits ONLY on LDS ops (h/rh handoff); global prefetch loads
// stay in flight (no vmcnt(0) drain). sched_barrier(0) on both sides pins
// pre-barrier ds_writes and post-barrier ds_reads (rule #18 hazard).
static __device__ __forceinline__ void block_sync_lds() {
    asm volatile("s_waitcnt lgkmcnt(0)" ::: "memory");
    __builtin_amdgcn_sched_barrier(0);
    __builtin_amdgcn_s_barrier();
    __builtin_amdgcn_sched_barrier(0);
}

__global__ __launch_bounds__(512, 2)
void gru_scan_kernel(const float* __restrict__ X,    // (B,T,D)
                     const float* __restrict__ Att,  // (B,T,1)
                     const float* __restrict__ Wu, const float* __restrict__ bu,
                     const float* __restrict__ Wr, const float* __restrict__ br,
                     const float* __restrict__ Wh, const float* __restrict__ bh,
                     float* __restrict__ out)        // (B,U)
{
    __shared__ __align__(16) unsigned short h_bf[XSTEP];   // 4352 B
    __shared__ __align__(16) unsigned short rh_bf[XSTEP];  // 4352 B

    const int tid  = threadIdx.x;
    const int wave = tid >> 6;    // 0..7, owns gatecols [16*wave, 16*wave+16)
    const int lane = tid & 63;
    const int q    = lane >> 4;
    const int ln   = lane & 15;
    const int b0   = blockIdx.x * BM;

    const float INVLN2 = 1.4426950408889634f;

    // ---- Weight A-fragments (16 gatecols per wave), bf16, ln2-prescaled.
    // lane holds gatecol m = ln (tile base 16*wave), k = 32*kt + 8*q + j.
    // GEMM1 k: [h|x] rows of Wu/Wr. GEMM2 k: [x | r*h] rows of Wh.
    bf16x8 wu[8], wr[8], wh[8];                     // 96 VGPRs
    f32x4 nbu, nbr, bh2;                            // C-operand bias preload
    {
        const int tb = 16 * wave;
        const int c  = tb + ln;
        const f32x4 bu4 = *(const f32x4*)&bu[tb + 4 * q];
        const f32x4 br4 = *(const f32x4*)&br[tb + 4 * q];
        const f32x4 bh4 = *(const f32x4*)&bh[tb + 4 * q];
        #pragma unroll
        for (int r = 0; r < 4; ++r) {
            nbu[r] = -bu4[r] * INVLN2;
            nbr[r] = -br4[r] * INVLN2;
            bh2[r] = 2.0f * bh4[r] * INVLN2;
        }
        #pragma unroll
        for (int kt = 0; kt < 8; ++kt) {
            const int k0 = 32 * kt + 8 * q;
            bf16x8 vu, vr, vh;
            #pragma unroll
            for (int j = 0; j < 8; ++j) {
                vu[j] = (short)f2bf(Wu[(k0 + j) * U_DIM + c] * -INVLN2);
                vr[j] = (short)f2bf(Wr[(k0 + j) * U_DIM + c] * -INVLN2);
                vh[j] = (short)f2bf(Wh[(k0 + j) * U_DIM + c] * (2.0f * INVLN2));
            }
            wu[kt] = vu; wr[kt] = vr; wh[kt] = vh;
        }
    }

    // per-lane global source pointers (all 8 waves read the same x lines -> L1/L2)
    const float* xrow = X + (size_t)(b0 + ln) * T_LEN * D_DIM + 8 * q;
    const float* arow = Att + (size_t)(b0 + ln) * T_LEN;

    // x prefetch registers: 8 f32x4 = one step's B-fragments (fp32)
    f32x4 px[8];
    #pragma unroll
    for (int kt = 0; kt < 4; ++kt) {
        px[2 * kt]     = *(const f32x4*)(xrow + 32 * kt);
        px[2 * kt + 1] = *(const f32x4*)(xrow + 32 * kt + 4);
    }
    const float a0 = arow[0];
    float attA = arow[1], attB = arow[2], attC = arow[3];   // 3-deep ring

    float hreg[4];                  // fp32 h: batch=ln, gatecol = 16w+4q+r
    f32x4 acc_r, acc_u, acc_h;      // x-part accumulators for the next step

    const int c8 = (2 * wave + (q >> 1)) * KCS + ln * 8 + (q & 1) * 4;

    // ---- step 0: h = 0 -> pure x-part (no h-part, no rh-part, no LDS read)
    {
        bf16x8 xf[4];
        #pragma unroll
        for (int kt = 0; kt < 4; ++kt) xf[kt] = pack8bf(px[2 * kt], px[2 * kt + 1]);
        // issue x loads for t=1
        #pragma unroll
        for (int kt = 0; kt < 4; ++kt) {
            px[2 * kt]     = *(const f32x4*)(xrow + D_DIM + 32 * kt);
            px[2 * kt + 1] = *(const f32x4*)(xrow + D_DIM + 32 * kt + 4);
        }
        f32x4 xu = nbu, xh = bh2;
        #pragma unroll
        for (int kt = 0; kt < 4; ++kt) {
            xu = MFMA(wu[kt + 4], xf[kt], xu, 0, 0, 0);
            xh = MFMA(wh[kt],     xf[kt], xh, 0, 0, 0);
        }
        #pragma unroll
        for (int r = 0; r < 4; ++r) {
            float u  = fast_rcp(1.0f + fast_exp2(xu[r])) * a0;          // sigmoid*a
            float hh = 1.0f - 2.0f * fast_rcp(1.0f + fast_exp2(xh[r])); // tanh
            hreg[r] = u * hh;                                            // (1-u)*0
        }
        {
            uint2 wv; wv.x = pkbf2(hreg[0], hreg[1]); wv.y = pkbf2(hreg[2], hreg[3]);
            *(uint2*)&h_bf[c8] = wv;
        }
        // x-part accumulators for t=1 (short vmcnt stall, step 0 only)
        bf16x8 x1[4];
        #pragma unroll
        for (int kt = 0; kt < 4; ++kt) x1[kt] = pack8bf(px[2 * kt], px[2 * kt + 1]);
        #pragma unroll
        for (int kt = 0; kt < 4; ++kt) {
            px[2 * kt]     = *(const f32x4*)(xrow + 2 * D_DIM + 32 * kt);
            px[2 * kt + 1] = *(const f32x4*)(xrow + 2 * D_DIM + 32 * kt + 4);
        }
        acc_r = nbr; acc_u = nbu; acc_h = bh2;
        #pragma unroll
        for (int kt = 0; kt < 4; ++kt) {
            acc_r = MFMA(wr[kt + 4], x1[kt], acc_r, 0, 0, 0);
            acc_u = MFMA(wu[kt + 4], x1[kt], acc_u, 0, 0, 0);
            acc_h = MFMA(wh[kt],     x1[kt], acc_h, 0, 0, 0);
        }
    }
    block_sync_lds();

    for (int t = 1; t < T_LEN; ++t) {
        // ---------- region 1: h-parts (r critical, 2+2 split) ----------
        bf16x8 hf[4];     // h(t-1) fragments, identical for all waves
        #pragma unroll
        for (int kt = 0; kt < 4; ++kt)
            hf[kt] = *(const bf16x8*)&h_bf[(4 * kt + q) * KCS + ln * 8];

        f32x4 ra = acc_r, rb = (f32x4)0.0f;
        ra = MFMA(wr[0], hf[0], ra, 0, 0, 0);
        rb = MFMA(wr[2], hf[2], rb, 0, 0, 0);
        ra = MFMA(wr[1], hf[1], ra, 0, 0, 0);
        rb = MFMA(wr[3], hf[3], rb, 0, 0, 0);
        #pragma unroll
        for (int kt = 0; kt < 4; ++kt)
            acc_u = MFMA(wu[kt], hf[kt], acc_u, 0, 0, 0);

        {   // r sigmoid; r*h -> LDS (one ds_write_b64)
            float rh[4];
            #pragma unroll
            for (int r = 0; r < 4; ++r) {
                float zr = ra[r] + rb[r];                   // = -z_r/ln2
                float rv = fast_rcp(1.0f + fast_exp2(zr));  // sigmoid
                rh[r] = rv * hreg[r];
            }
            uint2 wv; wv.x = pkbf2(rh[0], rh[1]); wv.y = pkbf2(rh[2], rh[3]);
            *(uint2*)&rh_bf[c8] = wv;
        }
        block_sync_lds();   // rh handoff (px/att loads stay in flight)

        // ---------- region 2 ----------
        bf16x8 rf[4];
        #pragma unroll
        for (int kt = 0; kt < 4; ++kt)
            rf[kt] = *(const bf16x8*)&rh_bf[(4 * kt + q) * KCS + ln * 8];

        // attention ring + u gate (VALU, fills rf latency)
        const float a_att = attA;
        attA = attB; attB = attC;
        attC = arow[(t + 3 < T_LEN) ? t + 3 : T_LEN - 1];
        float uq[4];
        #pragma unroll
        for (int r = 0; r < 4; ++r)
            uq[r] = fast_rcp(1.0f + fast_exp2(acc_u[r])) * a_att;  // sigmoid*a

        // candidate rh-part (critical, 2+2, seeded with ready x-part)
        f32x4 ha = acc_h, hb = (f32x4)0.0f;
        ha = MFMA(wh[4], rf[0], ha, 0, 0, 0);
        hb = MFMA(wh[6], rf[2], hb, 0, 0, 0);
        ha = MFMA(wh[5], rf[1], ha, 0, 0, 0);
        hb = MFMA(wh[7], rf[3], hb, 0, 0, 0);

        // tanh, h update, publish h
        #pragma unroll
        for (int r = 0; r < 4; ++r) {
            float z  = ha[r] + hb[r];                                // = 2*z_h/ln2
            float hh = 1.0f - 2.0f * fast_rcp(1.0f + fast_exp2(z));  // tanh
            float ho = hreg[r];
            hreg[r] = ho + uq[r] * (hh - ho);                        // u*hh+(1-u)*h
        }
        {
            uint2 wv; wv.x = pkbf2(hreg[0], hreg[1]); wv.y = pkbf2(hreg[2], hreg[3]);
            *(uint2*)&h_bf[c8] = wv;
        }

        // x-part accumulators for step t+1 (off critical path, fills barrier skew)
        {
            bf16x8 xf[4];
            #pragma unroll
            for (int kt = 0; kt < 4; ++kt)
                xf[kt] = pack8bf(px[2 * kt], px[2 * kt + 1]);
            const int tn = (t + 2 < T_LEN) ? t + 2 : T_LEN - 1;
            const float* xs = xrow + (size_t)tn * D_DIM;
            #pragma unroll
            for (int kt = 0; kt < 4; ++kt) {
                px[2 * kt]     = *(const f32x4*)(xs + 32 * kt);
                px[2 * kt + 1] = *(const f32x4*)(xs + 32 * kt + 4);
            }
            acc_r = nbr; acc_u = nbu; acc_h = bh2;
            #pragma unroll
            for (int kt = 0; kt < 4; ++kt) {
                acc_r = MFMA(wr[kt + 4], xf[kt], acc_r, 0, 0, 0);
                acc_u = MFMA(wu[kt + 4], xf[kt], acc_u, 0, 0, 0);
                acc_h = MFMA(wh[kt],     xf[kt], acc_h, 0, 0, 0);
            }
        }
        block_sync_lds();   // h handoff
    }

    // ---- store h_final: 4 consecutive gatecols per thread -> dwordx4 ----
    {
        f32x4 v;
        #pragma unroll
        for (int r = 0; r < 4; ++r) v[r] = hreg[r];
        *(f32x4*)&out[(size_t)(b0 + ln) * U_DIM + 16 * wave + 4 * q] = v;
    }
}

extern "C" void kernel_launch(void* const* d_in, const int* in_sizes, int n_in,
                              void* d_out, int out_size, void* d_ws, size_t ws_size,
                              hipStream_t stream) {
    const float* X   = (const float*)d_in[0];
    const float* Att = (const float*)d_in[1];
    const float* Wu  = (const float*)d_in[2];
    const float* bu  = (const float*)d_in[3];
    const float* Wr  = (const float*)d_in[4];
    const float* br  = (const float*)d_in[5];
    const float* Wh  = (const float*)d_in[6];
    const float* bh  = (const float*)d_in[7];
    float* out = (float*)d_out;

    gru_scan_kernel<<<dim3(2048 / BM), dim3(512), 0, stream>>>(
        X, Att, Wu, bu, Wr, br, Wh, bh, out);
}

// Round 4
// 465.923 us; speedup vs baseline: 1.4653x; 1.4653x over previous
//
#include <hip/hip_runtime.h>
#include <hip/hip_bf16.h>

// InterestEvolve: attention-modulated GRU scan. B=2048, T=200, D=128, U=128.
//
// R12 = R8 verbatim (the proven 254us/dispatch structure) with ONE change:
// CH 12 -> 24. Halves the number of synchronous staging phases (17 -> 9),
// halving their fixed overhead (HBM drain + barrier + write burst per chunk).
// Post-mortems R9-R11: global-direct per-wave x prefetch regressed (L1/VMEM
// re-pull scales with waves; per-step cvt on B-fragment path; 477us at 8
// waves). B-fragments must come from LDS; 8 waves / 2 per SIMD must stay.
//
// R8 structure: K-major padded LDS (KCS=136, conflict-free b128 reads AND
// staged writes), bias preloaded into MFMA C operand, v_cvt_pk_bf16_f32
// packing, 2+2 split critical chains, within-chunk x-part MFMA pipelining,
// synchronous chunk staging. 128 blocks x 512 threads (8 waves, 2/SIMD);
// wave owns 16 gatecols.

#define T_LEN 200
#define D_DIM 128
#define U_DIM 128
#define BM    16
#define CH    24
#define KCS   136          // ushorts per kchunk slot-row: 16 batch*8 + 8 pad
#define XSTEP (16 * KCS)   // ushorts per staged step (2176)

typedef __attribute__((ext_vector_type(8))) short bf16x8;
typedef __attribute__((ext_vector_type(4))) float f32x4;
typedef __attribute__((ext_vector_type(4))) unsigned int uint4v;

static __device__ __forceinline__ unsigned short f2bf(float f) {
    unsigned int u = __builtin_bit_cast(unsigned int, f);
    u += 0x7fffu + ((u >> 16) & 1u);       // round-to-nearest-even
    return (unsigned short)(u >> 16);
}
static __device__ __forceinline__ unsigned int pkbf2(float a, float b) {
    float2 t; t.x = a; t.y = b;
    __hip_bfloat162 v = __float22bfloat162_rn(t);   // v_cvt_pk_bf16_f32
    unsigned int u; __builtin_memcpy(&u, &v, 4);
    return u;
}
static __device__ __forceinline__ uint4v pack8u(float4 lo, float4 hi) {
    uint4v v;
    v[0] = pkbf2(lo.x, lo.y); v[1] = pkbf2(lo.z, lo.w);
    v[2] = pkbf2(hi.x, hi.y); v[3] = pkbf2(hi.z, hi.w);
    return v;
}
static __device__ __forceinline__ float fast_exp2(float x) {
#if __has_builtin(__builtin_amdgcn_exp2f)
    return __builtin_amdgcn_exp2f(x);
#else
    return exp2f(x);
#endif
}
static __device__ __forceinline__ float fast_rcp(float x) {
#if __has_builtin(__builtin_amdgcn_rcpf)
    return __builtin_amdgcn_rcpf(x);
#else
    return 1.0f / x;
#endif
}

__global__ __launch_bounds__(512, 2)
void gru_scan_kernel(const float* __restrict__ X,    // (B,T,D)
                     const float* __restrict__ Att,  // (B,T,1)
                     const float* __restrict__ Wu, const float* __restrict__ bu,
                     const float* __restrict__ Wr, const float* __restrict__ br,
                     const float* __restrict__ Wh, const float* __restrict__ bh,
                     float* __restrict__ out)        // (B,U)
{
    __shared__ __align__(16) unsigned short x_sm[CH * XSTEP];  // 104448 B
    __shared__ __align__(16) unsigned short h_bf[XSTEP];       // 4352 B
    __shared__ __align__(16) unsigned short rh_bf[XSTEP];      // 4352 B
    __shared__ float a_sm[CH * BM];                            // 1536 B

    const int tid  = threadIdx.x;
    const int wave = tid >> 6;    // owns gatecols [16*wave, 16*wave+16)
    const int lane = tid & 63;
    const int q    = lane >> 4;
    const int ln   = lane & 15;
    const int b0   = blockIdx.x * BM;

    const float INVLN2 = 1.4426950408889634f;

    // ---- Weight A-fragments (16 gatecols per wave), bf16, ln2-prescaled.
    // lane holds gatecol m = ln (tile base 16*wave), k = 32*kt + 8*q + j.
    // GEMM1 k: [h|x] rows of Wu/Wr. GEMM2 k: [x | r*h] rows of Wh.
    bf16x8 wu[8], wr[8], wh[8];
    f32x4 nbu, nbr, bh2;   // biases for gatecols 16w+4q+0..3 (C-operand preload)
    {
        const int tb = 16 * wave;
        const int c  = tb + ln;
        const f32x4 bu4 = *(const f32x4*)&bu[tb + 4 * q];
        const f32x4 br4 = *(const f32x4*)&br[tb + 4 * q];
        const f32x4 bh4 = *(const f32x4*)&bh[tb + 4 * q];
        #pragma unroll
        for (int r = 0; r < 4; ++r) {
            nbu[r] = -bu4[r] * INVLN2;
            nbr[r] = -br4[r] * INVLN2;
            bh2[r] = 2.0f * bh4[r] * INVLN2;
        }
        #pragma unroll
        for (int kt = 0; kt < 8; ++kt) {
            const int k0 = 32 * kt + 8 * q;
            bf16x8 vu, vr, vh;
            #pragma unroll
            for (int j = 0; j < 8; ++j) {
                vu[j] = (short)f2bf(Wu[(k0 + j) * U_DIM + c] * -INVLN2);
                vr[j] = (short)f2bf(Wr[(k0 + j) * U_DIM + c] * -INVLN2);
                vh[j] = (short)f2bf(Wh[(k0 + j) * U_DIM + c] * (2.0f * INVLN2));
            }
            wu[kt] = vu; wr[kt] = vr; wh[kt] = vh;
        }
    }

    float hreg[4] = {0.f, 0.f, 0.f, 0.f};   // fp32 h: batch=ln, gatecol=16w+4q+r

    // ---- clear ALL of h_bf / rh_bf (1088 uints each, incl. padding) ----
    {
        unsigned int* hz = (unsigned int*)h_bf;
        unsigned int* rz = (unsigned int*)rh_bf;
        for (int i = tid; i < XSTEP / 2; i += 512) { hz[i] = 0; rz[i] = 0; }
    }

    // staging map: thread = (s2 = tid>>8, srow = (tid>>4)&15, cs = tid&15)
    const int s2   = tid >> 8;
    const int srow = (tid >> 4) & 15;
    const int cs   = tid & 15;
    const float* xbase = X + (size_t)(b0 + srow) * T_LEN * D_DIM + cs * 8;

    int t0 = 0;
    for (int ch = 0; ch < (T_LEN + CH - 1) / CH; ++ch) {
        const int L = (t0 + CH <= T_LEN) ? CH : (T_LEN - t0);

        // ---- stage chunk synchronously: issue all loads, then pack+write ----
        {
            float4 px[CH];
            #pragma unroll
            for (int w2 = 0; w2 < CH / 2; ++w2) {
                int t = t0 + 2 * w2 + s2;
                t = (t < T_LEN) ? t : (T_LEN - 1);           // clamped, branchless
                const float* src = xbase + (size_t)t * D_DIM;
                px[2 * w2]     = *(const float4*)(src);
                px[2 * w2 + 1] = *(const float4*)(src + 4);
            }
            float a_px = 0.0f;
            if (tid < BM * CH) {
                int t = t0 + (tid >> 4);
                t = (t < T_LEN) ? t : (T_LEN - 1);
                a_px = Att[(size_t)(b0 + (tid & 15)) * T_LEN + t];
            }
            #pragma unroll
            for (int w2 = 0; w2 < CH / 2; ++w2) {
                const int s = 2 * w2 + s2;
                *(uint4v*)&x_sm[s * XSTEP + cs * KCS + srow * 8] =
                    pack8u(px[2 * w2], px[2 * w2 + 1]);
            }
            if (tid < BM * CH) a_sm[tid] = a_px;
        }
        __syncthreads();

        // ---- x-part accumulators for step 0 (bias preloaded into C) ----
        f32x4 acc_r, acc_u, acc_h;
        {
            bf16x8 xf[4];
            #pragma unroll
            for (int kt = 0; kt < 4; ++kt)
                xf[kt] = *(const bf16x8*)&x_sm[(4 * kt + q) * KCS + ln * 8];
            acc_r = nbr; acc_u = nbu; acc_h = bh2;
            #pragma unroll
            for (int kt = 0; kt < 4; ++kt) {
                acc_r = __builtin_amdgcn_mfma_f32_16x16x32_bf16(wr[kt + 4], xf[kt], acc_r, 0, 0, 0);
                acc_u = __builtin_amdgcn_mfma_f32_16x16x32_bf16(wu[kt + 4], xf[kt], acc_u, 0, 0, 0);
                acc_h = __builtin_amdgcn_mfma_f32_16x16x32_bf16(wh[kt],     xf[kt], acc_h, 0, 0, 0);
            }
        }

        for (int s = 0; s < L; ++s) {
            // ---------- region 1: h-parts (r critical, 2+2 split) ----------
            bf16x8 hf[4];
            #pragma unroll
            for (int kt = 0; kt < 4; ++kt)
                hf[kt] = *(const bf16x8*)&h_bf[(4 * kt + q) * KCS + ln * 8];
            const float a_att = a_sm[s * BM + ln];

            f32x4 ra = acc_r, rb = (f32x4)0.0f;
            ra = __builtin_amdgcn_mfma_f32_16x16x32_bf16(wr[0], hf[0], ra, 0, 0, 0);
            rb = __builtin_amdgcn_mfma_f32_16x16x32_bf16(wr[2], hf[2], rb, 0, 0, 0);
            ra = __builtin_amdgcn_mfma_f32_16x16x32_bf16(wr[1], hf[1], ra, 0, 0, 0);
            rb = __builtin_amdgcn_mfma_f32_16x16x32_bf16(wr[3], hf[3], rb, 0, 0, 0);
            #pragma unroll
            for (int kt = 0; kt < 4; ++kt)
                acc_u = __builtin_amdgcn_mfma_f32_16x16x32_bf16(wu[kt], hf[kt], acc_u, 0, 0, 0);

            {   // r sigmoid; r*h -> LDS (one ds_write_b64)
                float rh[4];
                #pragma unroll
                for (int r = 0; r < 4; ++r) {
                    float zr = ra[r] + rb[r];                   // = -z_r/ln2
                    float rv = fast_rcp(1.0f + fast_exp2(zr));  // sigmoid
                    rh[r] = rv * hreg[r];
                }
                uint2 wv; wv.x = pkbf2(rh[0], rh[1]); wv.y = pkbf2(rh[2], rh[3]);
                const int c8 = 2 * wave + (q >> 1);
                *(uint2*)&rh_bf[c8 * KCS + ln * 8 + (q & 1) * 4] = wv;
            }
            __syncthreads();   // rh handoff

            // ---------- region 2 ----------
            bf16x8 rf[4];
            #pragma unroll
            for (int kt = 0; kt < 4; ++kt)
                rf[kt] = *(const bf16x8*)&rh_bf[(4 * kt + q) * KCS + ln * 8];

            // u gate (off critical path)
            float uq[4];
            #pragma unroll
            for (int r = 0; r < 4; ++r) {
                float u = fast_rcp(1.0f + fast_exp2(acc_u[r]));  // sigmoid (-z/ln2 form)
                uq[r] = u * a_att;
            }

            // candidate: rh-part (critical, 2+2 split)
            f32x4 ha = acc_h, hb = (f32x4)0.0f;
            ha = __builtin_amdgcn_mfma_f32_16x16x32_bf16(wh[4], rf[0], ha, 0, 0, 0);
            hb = __builtin_amdgcn_mfma_f32_16x16x32_bf16(wh[6], rf[2], hb, 0, 0, 0);
            ha = __builtin_amdgcn_mfma_f32_16x16x32_bf16(wh[5], rf[1], ha, 0, 0, 0);
            hb = __builtin_amdgcn_mfma_f32_16x16x32_bf16(wh[7], rf[3], hb, 0, 0, 0);

            // tanh, h update, publish h
            #pragma unroll
            for (int r = 0; r < 4; ++r) {
                float z  = ha[r] + hb[r];                               // = 2*z_h/ln2
                float hh = 1.0f - 2.0f * fast_rcp(1.0f + fast_exp2(z)); // tanh
                float ho = hreg[r];
                hreg[r] = ho + uq[r] * (hh - ho);                       // u*hh + (1-u)*h
            }
            {
                uint2 wv; wv.x = pkbf2(hreg[0], hreg[1]); wv.y = pkbf2(hreg[2], hreg[3]);
                const int c8 = 2 * wave + (q >> 1);
                *(uint2*)&h_bf[c8 * KCS + ln * 8 + (q & 1) * 4] = wv;
            }

            // x-part accumulators for step s+1 (same chunk, off critical path)
            if (s + 1 < L) {
                bf16x8 xf[4];
                #pragma unroll
                for (int kt = 0; kt < 4; ++kt)
                    xf[kt] = *(const bf16x8*)&x_sm[(s + 1) * XSTEP + (4 * kt + q) * KCS + ln * 8];
                acc_r = nbr; acc_u = nbu; acc_h = bh2;
                #pragma unroll
                for (int kt = 0; kt < 4; ++kt) {
                    acc_r = __builtin_amdgcn_mfma_f32_16x16x32_bf16(wr[kt + 4], xf[kt], acc_r, 0, 0, 0);
                    acc_u = __builtin_amdgcn_mfma_f32_16x16x32_bf16(wu[kt + 4], xf[kt], acc_u, 0, 0, 0);
                    acc_h = __builtin_amdgcn_mfma_f32_16x16x32_bf16(wh[kt],     xf[kt], acc_h, 0, 0, 0);
                }
            }
            __syncthreads();   // h handoff
        }
        t0 += CH;
    }

    // ---- store h_final: 4 consecutive gatecols per thread -> dwordx4 ----
    {
        f32x4 v;
        #pragma unroll
        for (int r = 0; r < 4; ++r) v[r] = hreg[r];
        *(f32x4*)&out[(size_t)(b0 + ln) * U_DIM + 16 * wave + 4 * q] = v;
    }
}

extern "C" void kernel_launch(void* const* d_in, const int* in_sizes, int n_in,
                              void* d_out, int out_size, void* d_ws, size_t ws_size,
                              hipStream_t stream) {
    const float* X   = (const float*)d_in[0];
    const float* Att = (const float*)d_in[1];
    const float* Wu  = (const float*)d_in[2];
    const float* bu  = (const float*)d_in[3];
    const float* Wr  = (const float*)d_in[4];
    const float* br  = (const float*)d_in[5];
    const float* Wh  = (const float*)d_in[6];
    const float* bh  = (const float*)d_in[7];
    float* out = (float*)d_out;

    gru_scan_kernel<<<dim3(2048 / BM), dim3(512), 0, stream>>>(
        X, Att, Wu, bu, Wr, br, Wh, bh, out);
}